// Round 1
// baseline (974.360 us; speedup 1.0000x reference)
//
#include <hip/hip_runtime.h>

// contrib = KEHALF * f * Zi*Zj / rij ; out[idx_i] += contrib
static constexpr float KEHALF = 7.199822675975274f; // 14.399645351950548 / 2

// ---------------------------------------------------------------------------
// Kernel 1: compute softplus'd constants once (single thread).
// consts layout: [0]=sp(apow) [1]=sp(adiv) [2..5]=c1n..c4n [6..9]=sp(a1..a4)
// ---------------------------------------------------------------------------
__global__ void zbl_consts_kernel(const float* __restrict__ adiv,
                                  const float* __restrict__ apow,
                                  const float* __restrict__ c1,
                                  const float* __restrict__ c2,
                                  const float* __restrict__ c3,
                                  const float* __restrict__ c4,
                                  const float* __restrict__ a1,
                                  const float* __restrict__ a2,
                                  const float* __restrict__ a3,
                                  const float* __restrict__ a4,
                                  float* __restrict__ consts) {
    if (threadIdx.x == 0 && blockIdx.x == 0) {
        auto sp = [](float x) { return log1pf(expf(x)); }; // accurate, runs once
        float c1p = sp(*c1), c2p = sp(*c2), c3p = sp(*c3), c4p = sp(*c4);
        float inv = 1.0f / (c1p + c2p + c3p + c4p);
        consts[0] = sp(*apow);
        consts[1] = sp(*adiv);
        consts[2] = c1p * inv;
        consts[3] = c2p * inv;
        consts[4] = c3p * inv;
        consts[5] = c4p * inv;
        consts[6] = sp(*a1);
        consts[7] = sp(*a2);
        consts[8] = sp(*a3);
        consts[9] = sp(*a4);
    }
}

// ---------------------------------------------------------------------------
// Kernel 2: per-atom screened charge z[i] = Zf[i] ^ sp(apow)
// ---------------------------------------------------------------------------
__global__ void zbl_atom_kernel(const float* __restrict__ Zf,
                                const float* __restrict__ consts,
                                float* __restrict__ z, int N) {
    int i = blockIdx.x * blockDim.x + threadIdx.x;
    if (i < N) {
        z[i] = powf(Zf[i], consts[0]);
    }
}

// ---------------------------------------------------------------------------
// Kernel 3: per-pair energy + atomic scatter. 4 pairs per thread (float4/int4).
// ---------------------------------------------------------------------------
__global__ void __launch_bounds__(256)
zbl_pair_kernel(const float4* __restrict__ rij4,
                const float4* __restrict__ cut4,
                const int4* __restrict__ ii4,
                const int4* __restrict__ jj4,
                const float* __restrict__ Zf,
                const float* __restrict__ z,
                const float* __restrict__ consts,
                float* __restrict__ out,
                int P4, int P) {
    int t = blockIdx.x * blockDim.x + threadIdx.x;
    if (t >= P4) return;

    // Uniform constants (L2-hit loads; negligible vs 16 B/pair stream)
    const float sp_adiv = consts[1];
    const float c1n = consts[2], c2n = consts[3], c3n = consts[4], c4n = consts[5];
    const float a1 = consts[6], a2 = consts[7], a3 = consts[8], a4 = consts[9];

    float4 r4 = rij4[t];
    float4 c4v = cut4[t];
    int4 i4 = ii4[t];
    int4 j4 = jj4[t];

    const float* rr = reinterpret_cast<const float*>(&r4);
    const float* cc = reinterpret_cast<const float*>(&c4v);
    const int* ii = reinterpret_cast<const int*>(&i4);
    const int* jj = reinterpret_cast<const int*>(&j4);

#pragma unroll
    for (int k = 0; k < 4; ++k) {
        int i = ii[k], j = jj[k];
        float r = rr[k];
        float cut = cc[k];
        float a = (z[i] + z[j]) * sp_adiv;
        float ar = a * r;
        float f = c1n * __expf(-a1 * ar)
                + c2n * __expf(-a2 * ar)
                + c3n * __expf(-a3 * ar)
                + c4n * __expf(-a4 * ar);
        float zizj = Zf[i] * Zf[j];
        float contrib = KEHALF * f * cut * zizj * __builtin_amdgcn_rcpf(r);
        atomicAdd(&out[i], contrib);
    }

    // Scalar tail (P not divisible by 4) — handled by thread 0.
    if (t == 0) {
        const float* rij = reinterpret_cast<const float*>(rij4);
        const float* cutv = reinterpret_cast<const float*>(cut4);
        const int* idx_i = reinterpret_cast<const int*>(ii4);
        const int* idx_j = reinterpret_cast<const int*>(jj4);
        for (int p = P4 * 4; p < P; ++p) {
            int i = idx_i[p], j = idx_j[p];
            float r = rij[p];
            float a = (z[i] + z[j]) * sp_adiv;
            float ar = a * r;
            float f = c1n * __expf(-a1 * ar)
                    + c2n * __expf(-a2 * ar)
                    + c3n * __expf(-a3 * ar)
                    + c4n * __expf(-a4 * ar);
            float contrib = KEHALF * f * cutv[p] * Zf[i] * Zf[j] *
                            __builtin_amdgcn_rcpf(r);
            atomicAdd(&out[i], contrib);
        }
    }
}

// ---------------------------------------------------------------------------
extern "C" void kernel_launch(void* const* d_in, const int* in_sizes, int n_in,
                              void* d_out, int out_size, void* d_ws, size_t ws_size,
                              hipStream_t stream) {
    // Input order per setup_inputs():
    // 0:N 1:Zf 2:rij 3:cutoff_values 4:idx_i 5:idx_j
    // 6:adiv 7:apow 8:c1 9:c2 10:c3 11:c4 12:a1 13:a2 14:a3 15:a4
    const float* Zf = (const float*)d_in[1];
    const float* rij = (const float*)d_in[2];
    const float* cut = (const float*)d_in[3];
    const int* idx_i = (const int*)d_in[4];
    const int* idx_j = (const int*)d_in[5];

    const int N = in_sizes[1];
    const int P = in_sizes[2];
    const int P4 = P / 4;

    // Workspace layout: z[N] floats, then consts[10] floats.
    float* z = (float*)d_ws;
    float* consts = z + N;

    float* out = (float*)d_out;

    // Output must be zeroed every call (harness poisons with 0xAA).
    hipMemsetAsync(out, 0, (size_t)out_size * sizeof(float), stream);

    zbl_consts_kernel<<<1, 64, 0, stream>>>(
        (const float*)d_in[6], (const float*)d_in[7],
        (const float*)d_in[8], (const float*)d_in[9],
        (const float*)d_in[10], (const float*)d_in[11],
        (const float*)d_in[12], (const float*)d_in[13],
        (const float*)d_in[14], (const float*)d_in[15], consts);

    zbl_atom_kernel<<<(N + 255) / 256, 256, 0, stream>>>(Zf, consts, z, N);

    zbl_pair_kernel<<<(P4 + 255) / 256, 256, 0, stream>>>(
        (const float4*)rij, (const float4*)cut,
        (const int4*)idx_i, (const int4*)idx_j,
        Zf, z, consts, out, P4, P);
}